// Round 12
// baseline (398.442 us; speedup 1.0000x reference)
//
#include <hip/hip_runtime.h>

#define NN 50000
#define NE 800000
#define EPSV 1e-5f

typedef unsigned int u32;

// ws: aggx/yb [NN*64] | xb [NN*32] | st [1024] | deg [NN] | cur [NN] | csr [NE] | psum/pssq [2*50048]
#define WS_NEEDED ((size_t)(NN * 64 + NN * 32 + 1024 + NN + NN + NE + 2 * 50048) * 4)

__global__ void k_fallback(float* __restrict__ out) {
  int i = blockIdx.x * 256 + threadIdx.x;
  if (i < NN * 128) out[i] = 2.0f;
}

// mode: 1 = int64 (odd 32-bit words of first 32 values all zero), 0 = int32.
__global__ void k_detect(const int* __restrict__ ei, int* __restrict__ mode) {
  if (threadIdx.x == 0) {
    int all0 = 1;
    for (int i = 1; i < 64; i += 2) all0 &= (ei[i] == 0);
    *mode = all0;
  }
}

__device__ __forceinline__ void load_edge(const int* __restrict__ ei, int m, int e,
                                          int& src, int& dst) {
  if (m) { src = ei[e << 1]; dst = ei[(NE + e) << 1]; }
  else   { src = ei[e];      dst = ei[NE + e]; }
  src = min(max(src, 0), NN - 1);
  dst = min(max(dst, 0), NN - 1);
}

__global__ __launch_bounds__(256) void k_hist(
    const int* __restrict__ ei, const int* __restrict__ mode, int* __restrict__ deg) {
  int e = blockIdx.x * 256 + threadIdx.x;
  int src, dst;
  load_edge(ei, *mode, e, src, dst);
  atomicAdd(&deg[dst], 1);
}

// Stage 1: per-256-chunk sums of deg. 196 blocks.
__global__ __launch_bounds__(256) void k_scan1(
    const int* __restrict__ deg, int* __restrict__ bsum) {
  const int b = blockIdx.x, t = threadIdx.x;
  const int lane = t & 63, wave = t >> 6;
  int idx = b * 256 + t;
  int v = (idx < NN) ? deg[idx] : 0;
  for (int off = 32; off > 0; off >>= 1) v += __shfl_down(v, off);
  __shared__ int wt[4];
  if (lane == 0) wt[wave] = v;
  __syncthreads();
  if (t == 0) bsum[b] = wt[0] + wt[1] + wt[2] + wt[3];
}

// Stage 2: block offset = reduce(bsum[0..b)), then block-wide exclusive scan.
__global__ __launch_bounds__(256) void k_scan3(
    const int* __restrict__ deg, const int* __restrict__ bsum, int* __restrict__ cur) {
  const int b = blockIdx.x, t = threadIdx.x;
  const int lane = t & 63, wave = t >> 6;
  __shared__ int wt[4];
  __shared__ int boff;
  int pv = (t < b) ? bsum[t] : 0;  // b <= 195 < 256
  int r = pv;
  for (int off = 32; off > 0; off >>= 1) r += __shfl_down(r, off);
  if (lane == 0) wt[wave] = r;
  __syncthreads();
  if (t == 0) boff = wt[0] + wt[1] + wt[2] + wt[3];
  __syncthreads();
  int idx = b * 256 + t;
  int v = (idx < NN) ? deg[idx] : 0;
  int incl = v;
  for (int off = 1; off < 64; off <<= 1) {
    int u = __shfl_up(incl, off);
    if (lane >= off) incl += u;
  }
  if (lane == 63) wt[wave] = incl;
  __syncthreads();
  int woff = 0;
  for (int w = 0; w < wave; ++w) woff += wt[w];
  if (idx < NN) cur[idx] = boff + woff + incl - v;
}

__global__ __launch_bounds__(256) void k_place(
    const int* __restrict__ ei, const int* __restrict__ mode,
    int* __restrict__ cur, int* __restrict__ csr) {
  int e = blockIdx.x * 256 + threadIdx.x;
  int src, dst;
  load_edge(ei, *mode, e, src, dst);
  int pos = atomicAdd(&cur[dst], 1);
  csr[pos] = src;
}

__device__ __forceinline__ u32 pack_bf16(float lo, float hi) {
  union { float f; u32 u; } a, b;
  a.f = lo; b.f = hi;
  u32 ua = a.u + 0x7fffu + ((a.u >> 16) & 1u);
  u32 ub = b.u + 0x7fffu + ((b.u >> 16) & 1u);
  return (ua >> 16) | (ub & 0xffff0000u);
}
#define BFLO(u) __uint_as_float((u) << 16)
#define BFHI(u) __uint_as_float((u) & 0xffff0000u)

// xb[n*32+c] = pack(x[n*64+2c], x[n*64+2c+1])
__global__ __launch_bounds__(256) void k_pack(
    const float* __restrict__ x, u32* __restrict__ xb) {
  int i = blockIdx.x * 256 + threadIdx.x;  // over NN*32
  int n = i >> 5, c = i & 31;
  float2 v = *(const float2*)&x[n * 64 + c * 2];
  xb[i] = pack_bf16(v.x, v.y);
}

// aggx[n] = sum over incoming edges of unpack(xb[src]). 16 lanes/node, uint2/lane.
__global__ __launch_bounds__(256) void k_gather_xb(
    const u32* __restrict__ xb, const int* __restrict__ csr,
    const int* __restrict__ cur, const int* __restrict__ deg,
    float* __restrict__ aggx) {
  int tid = blockIdx.x * 256 + threadIdx.x;
  int n = tid >> 4, L = tid & 15;
  int end = cur[n];
  int i = end - deg[n];
  float a0 = 0.f, a1 = 0.f, a2 = 0.f, a3 = 0.f;
  float b0 = 0.f, b1 = 0.f, b2 = 0.f, b3 = 0.f;
  for (; i + 1 < end; i += 2) {
    int s0 = csr[i], s1 = csr[i + 1];
    uint2 u = *(const uint2*)&xb[s0 * 32 + 2 * L];
    uint2 w = *(const uint2*)&xb[s1 * 32 + 2 * L];
    a0 += BFLO(u.x); a1 += BFHI(u.x); a2 += BFLO(u.y); a3 += BFHI(u.y);
    b0 += BFLO(w.x); b1 += BFHI(w.x); b2 += BFLO(w.y); b3 += BFHI(w.y);
  }
  if (i < end) {
    int s0 = csr[i];
    uint2 u = *(const uint2*)&xb[s0 * 32 + 2 * L];
    a0 += BFLO(u.x); a1 += BFHI(u.x); a2 += BFLO(u.y); a3 += BFHI(u.y);
  }
  *(float4*)&aggx[n * 64 + 4 * L] =
      make_float4(a0 + b0, a1 + b1, a2 + b2, a3 + b3);
}

// h = [aggx | x] @ [Wrel0 ; Wroot0] (M=NN, K=128, N=128) + fused BN0 stat partials.
// Staging remap vs prior round: consecutive lanes write consecutive `node`
// (LDS stride 1) -> conflict-free; old map had lane-stride 4*132 = 16 mod 32
// (16-way conflict). Same data, same addresses, same barriers.
__global__ __launch_bounds__(256) void k_gemm_a(
    const float* __restrict__ x, const float* __restrict__ aggx,
    const float* __restrict__ Wrel, const float* __restrict__ Wroot,
    float* __restrict__ h, float* __restrict__ psum, float* __restrict__ pssq) {
  __shared__ float smem[16 * 132 + 16 * 128];
  float* As = smem;             // [kk][node], pad 132
  float* Bs = smem + 16 * 132;  // [kk][j]
  const int tid = threadIdx.x;
  const int nb = blockIdx.x * 128;
  const int tx = tid & 15;
  const int ty = tid >> 4;
  float acc[8][8];
#pragma unroll
  for (int i = 0; i < 8; ++i)
#pragma unroll
    for (int m = 0; m < 8; ++m) acc[i][m] = 0.f;

  for (int k0 = 0; k0 < 128; k0 += 16) {
    const float* Asrc = (k0 < 64) ? aggx : x;
    const float* Bsrc = (k0 < 64) ? Wrel : Wroot;
    const int kbase = (k0 < 64) ? k0 : (k0 - 64);
    __syncthreads();
#pragma unroll
    for (int it = 0; it < 2; ++it) {  // A: 128 nodes x 16 k = 512 float4
      int fid = tid + 256 * it;
      int node = fid & 127, kq = (fid >> 7) << 2;  // lane-stride-1 LDS writes
      int n = nb + node;
      float4 v = (n < NN) ? *(const float4*)&Asrc[n * 64 + kbase + kq]
                          : make_float4(0.f, 0.f, 0.f, 0.f);
      As[(kq + 0) * 132 + node] = v.x;
      As[(kq + 1) * 132 + node] = v.y;
      As[(kq + 2) * 132 + node] = v.z;
      As[(kq + 3) * 132 + node] = v.w;
    }
#pragma unroll
    for (int it = 0; it < 2; ++it) {  // B: 16 x 128 = 512 float4
      int fid = tid + 256 * it;
      int kk = fid >> 5, j4 = (fid & 31) << 2;
      *(float4*)&Bs[kk * 128 + j4] = *(const float4*)&Bsrc[(kbase + kk) * 128 + j4];
    }
    __syncthreads();
#pragma unroll 4
    for (int kk = 0; kk < 16; ++kk) {
      float a[8], b[8];
      *(float4*)&a[0] = *(const float4*)&As[kk * 132 + ty * 8];
      *(float4*)&a[4] = *(const float4*)&As[kk * 132 + ty * 8 + 4];
#pragma unroll
      for (int m = 0; m < 8; ++m) b[m] = Bs[kk * 128 + tx + 16 * m];
#pragma unroll
      for (int i = 0; i < 8; ++i)
#pragma unroll
        for (int m = 0; m < 8; ++m) acc[i][m] += a[i] * b[m];
    }
  }
#pragma unroll
  for (int i = 0; i < 8; ++i) {
    int n = nb + ty * 8 + i;
    if (n < NN) {
#pragma unroll
      for (int m = 0; m < 8; ++m) h[n * 128 + tx + 16 * m] = acc[i][m];
    }
  }
  float ps[8], qs[8];
#pragma unroll
  for (int m = 0; m < 8; ++m) {
    float s = 0.f, q = 0.f;
#pragma unroll
    for (int i = 0; i < 8; ++i) { s += acc[i][m]; q += acc[i][m] * acc[i][m]; }
    ps[m] = s; qs[m] = q;
  }
  __syncthreads();  // safe LDS reuse
  float* S = smem;          // [16][128]
  float* Q = smem + 2048;   // [16][128]
#pragma unroll
  for (int m = 0; m < 8; ++m) {
    S[ty * 128 + tx + 16 * m] = ps[m];
    Q[ty * 128 + tx + 16 * m] = qs[m];
  }
  __syncthreads();
  if (tid < 128) {
    float s = 0.f, q = 0.f;
#pragma unroll
    for (int g = 0; g < 16; ++g) { s += S[g * 128 + tid]; q += Q[g * 128 + tid]; }
    psum[blockIdx.x * 128 + tid] = s;
    pssq[blockIdx.x * 128 + tid] = q;
  }
}

// Stage 1 BN stats for layer 2: 256 blocks of per-block channel partials.
__global__ __launch_bounds__(256) void k_stats_part(
    const float* __restrict__ h, float* __restrict__ psum, float* __restrict__ pssq) {
  const int p = blockIdx.x;
  const int t = threadIdx.x;
  const int c = t & 127, half = t >> 7;
  float s = 0.f, q = 0.f;
  const int base = p * 196;
  for (int i = half; i < 196; i += 2) {
    int n = base + i;
    if (n < NN) {
      float v = h[n * 128 + c];
      s += v; q += v * v;
    }
  }
  __shared__ float ls[128], lq[128];
  if (half) { ls[c] = s; lq[c] = q; }
  __syncthreads();
  if (!half) {
    psum[p * 128 + c] = s + ls[c];
    pssq[p * 128 + c] = q + lq[c];
  }
}

// Parallel partial reduction -> scale/shift. 128 blocks (one per channel) x 64 lanes.
__global__ __launch_bounds__(64) void k_bnfin(
    const float* __restrict__ psum, const float* __restrict__ pssq,
    const float* __restrict__ gamma, const float* __restrict__ beta,
    float* __restrict__ scale, float* __restrict__ shift, int P) {
  const int c = blockIdx.x;
  const int t = threadIdx.x;
  float S = 0.f, Q = 0.f;
  for (int p = t; p < P; p += 64) {
    S += psum[p * 128 + c];
    Q += pssq[p * 128 + c];
  }
  for (int off = 32; off > 0; off >>= 1) {
    S += __shfl_down(S, off);
    Q += __shfl_down(Q, off);
  }
  if (t == 0) {
    float mean = S * (1.0f / NN);
    float var = fmaxf(Q * (1.0f / NN) - mean * mean, 0.f);
    float sc = gamma[c] * rsqrtf(var + EPSV);
    scale[c] = sc;
    shift[c] = beta[c] - mean * sc;
  }
}

// t = relu(bn(h)); yb = bf16(t @ Wrel1) packed; h <- t @ Wroot1 (in place).
// Staging remap: consecutive lanes -> consecutive node (stride-1 LDS writes,
// conflict-free); old map had lane-stride 4*68 = 16 mod 32 (16-way conflict,
// the measured 3.0M SQ_LDS_BANK_CONFLICT).
__global__ __launch_bounds__(256) void k_gemm_b(
    const float* __restrict__ Wrel, const float* __restrict__ Wroot,
    const float* __restrict__ scale, const float* __restrict__ shift,
    u32* __restrict__ yb, float* __restrict__ h) {
  __shared__ float As[128 * 68];  // [k][node], pad 68
  __shared__ float Bs[16 * 256];
  const int tid = threadIdx.x;
  const int nb = blockIdx.x * 64;
  const int tx = tid & 31;
  const int ty = tid >> 5;
#pragma unroll
  for (int it = 0; it < 8; ++it) {  // stage A = relu(bn(h)) transposed
    int fid = tid + 256 * it;
    int node = fid & 63, kq = (fid >> 6) << 2;  // lane-stride-1 LDS writes
    int n = nb + node;
    float4 v = (n < NN) ? *(const float4*)&h[n * 128 + kq]
                        : make_float4(0.f, 0.f, 0.f, 0.f);
    float4 sc = *(const float4*)&scale[kq];
    float4 sh = *(const float4*)&shift[kq];
    As[(kq + 0) * 68 + node] = fmaxf(v.x * sc.x + sh.x, 0.f);
    As[(kq + 1) * 68 + node] = fmaxf(v.y * sc.y + sh.y, 0.f);
    As[(kq + 2) * 68 + node] = fmaxf(v.z * sc.z + sh.z, 0.f);
    As[(kq + 3) * 68 + node] = fmaxf(v.w * sc.w + sh.w, 0.f);
  }
  float acc[8][8];
#pragma unroll
  for (int i = 0; i < 8; ++i)
#pragma unroll
    for (int m = 0; m < 8; ++m) acc[i][m] = 0.f;

  for (int k0 = 0; k0 < 128; k0 += 16) {
    __syncthreads();
#pragma unroll
    for (int it = 0; it < 4; ++it) {  // B: 16 x 256
      int fid = tid + 256 * it;
      int kk = fid >> 6, j4 = (fid & 63) << 2;
      const float* Bsrc = (j4 < 128) ? &Wrel[(k0 + kk) * 128 + j4]
                                     : &Wroot[(k0 + kk) * 128 + (j4 - 128)];
      *(float4*)&Bs[kk * 256 + j4] = *(const float4*)Bsrc;
    }
    __syncthreads();
#pragma unroll 4
    for (int kk = 0; kk < 16; ++kk) {
      float a[8], b[8];
      *(float4*)&a[0] = *(const float4*)&As[(k0 + kk) * 68 + ty * 8];
      *(float4*)&a[4] = *(const float4*)&As[(k0 + kk) * 68 + ty * 8 + 4];
#pragma unroll
      for (int m = 0; m < 8; ++m) b[m] = Bs[kk * 256 + tx + 32 * m];
#pragma unroll
      for (int i = 0; i < 8; ++i)
#pragma unroll
        for (int m = 0; m < 8; ++m) acc[i][m] += a[i] * b[m];
    }
  }
#pragma unroll
  for (int i = 0; i < 8; ++i) {
    int n = nb + ty * 8 + i;
    if (n < NN) {
      yb[n * 64 + tx]      = pack_bf16(acc[i][0], acc[i][1]);
      yb[n * 64 + tx + 32] = pack_bf16(acc[i][2], acc[i][3]);
      float* hp = h + n * 128;
      hp[tx]      = acc[i][4];
      hp[tx + 32] = acc[i][5];
      hp[tx + 64] = acc[i][6];
      hp[tx + 96] = acc[i][7];
    }
  }
}

// h[n] += sum over incoming edges of unpack(yb[src]). 16 lanes/node, uint4/lane.
__global__ __launch_bounds__(256) void k_gather2(
    const u32* __restrict__ yb, const int* __restrict__ csr,
    const int* __restrict__ cur, const int* __restrict__ deg,
    float* __restrict__ h) {
  int tid = blockIdx.x * 256 + threadIdx.x;
  int n = tid >> 4;
  int L = tid & 15;
  int base = L << 2;
  int c0 = (base & 31) + ((base >> 5) << 6);
  int end = cur[n];
  int i = end - deg[n];
  float lo0 = 0.f, lo1 = 0.f, lo2 = 0.f, lo3 = 0.f;
  float hi0 = 0.f, hi1 = 0.f, hi2 = 0.f, hi3 = 0.f;
  for (; i < end; ++i) {
    int s = csr[i];
    uint4 v = *(const uint4*)&yb[s * 64 + base];
    lo0 += BFLO(v.x); hi0 += BFHI(v.x);
    lo1 += BFLO(v.y); hi1 += BFHI(v.y);
    lo2 += BFLO(v.z); hi2 += BFHI(v.z);
    lo3 += BFLO(v.w); hi3 += BFHI(v.w);
  }
  float4 A = *(const float4*)&h[n * 128 + c0];
  float4 B = *(const float4*)&h[n * 128 + c0 + 32];
  *(float4*)&h[n * 128 + c0] =
      make_float4(A.x + lo0, A.y + lo1, A.z + lo2, A.w + lo3);
  *(float4*)&h[n * 128 + c0 + 32] =
      make_float4(B.x + hi0, B.y + hi1, B.z + hi2, B.w + hi3);
}

__global__ __launch_bounds__(256) void k_final(
    const float* __restrict__ h, const float* __restrict__ scale,
    const float* __restrict__ shift, float* __restrict__ out) {
  int tid = blockIdx.x * 256 + threadIdx.x;
  int base = tid << 2;
  int f4 = base & 127;
  float4 v = *(const float4*)&h[base];
  float4 sc = *(const float4*)&scale[f4];
  float4 sh = *(const float4*)&shift[f4];
  *(float4*)&out[base] = make_float4(v.x * sc.x + sh.x, v.y * sc.y + sh.y,
                                     v.z * sc.z + sh.z, v.w * sc.w + sh.w);
}

extern "C" void kernel_launch(void* const* d_in, const int* in_sizes, int n_in,
                              void* d_out, int out_size, void* d_ws, size_t ws_size,
                              hipStream_t stream) {
  if (ws_size < WS_NEEDED) {
    k_fallback<<<(NN * 128 + 255) / 256, 256, 0, stream>>>((float*)d_out);
    return;
  }
  const float* x      = (const float*)d_in[0];
  const int*   ei     = (const int*)d_in[1];
  const float* Wrel0  = (const float*)d_in[2];
  // d_in[3] = b_rel0: per-channel constant pre-BN -> cancels in BN, unused
  const float* Wroot0 = (const float*)d_in[4];
  const float* gamma0 = (const float*)d_in[5];
  const float* beta0  = (const float*)d_in[6];
  const float* Wrel1  = (const float*)d_in[7];
  // d_in[8] = b_rel1: unused (cancels in BN)
  const float* Wroot1 = (const float*)d_in[9];
  const float* gamma1 = (const float*)d_in[10];
  const float* beta1  = (const float*)d_in[11];

  float* aggx = (float*)d_ws;            // NN*64 (reused as yb after gemm_a)
  u32*   yb   = (u32*)d_ws;
  u32*   xb   = (u32*)(aggx + NN * 64);  // NN*32
  float* st   = (float*)(xb + NN * 32);  // 1024 floats
  float* scale0 = st;       float* shift0 = st + 128;
  float* scale1 = st + 256; float* shift1 = st + 384;
  int* mode = (int*)(st + 512);
  int* bsum = (int*)(st + 576);          // 196 ints
  int* deg = (int*)(st + 1024);          // NN
  int* cur = deg + NN;                   // NN
  int* csr = cur + NN;                   // NE
  float* psum = (float*)(csr + NE);      // 50048
  float* pssq = psum + 50048;            // 50048
  float* h = (float*)d_out;              // h lives in d_out; k_final is in-place

  hipMemsetAsync(deg, 0, (size_t)NN * 4, stream);
  k_detect<<<1, 64, 0, stream>>>(ei, mode);
  k_hist<<<NE / 256, 256, 0, stream>>>(ei, mode, deg);
  k_scan1<<<196, 256, 0, stream>>>(deg, bsum);
  k_scan3<<<196, 256, 0, stream>>>(deg, bsum, cur);
  k_place<<<NE / 256, 256, 0, stream>>>(ei, mode, cur, csr);

  k_pack<<<(NN * 32) / 256, 256, 0, stream>>>(x, xb);
  k_gather_xb<<<(NN * 16) / 256, 256, 0, stream>>>(xb, csr, cur, deg, aggx);
  k_gemm_a<<<(NN + 127) / 128, 256, 0, stream>>>(x, aggx, Wrel0, Wroot0, h, psum, pssq);
  k_bnfin<<<128, 64, 0, stream>>>(psum, pssq, gamma0, beta0, scale0, shift0, 391);
  k_gemm_b<<<(NN + 63) / 64, 256, 0, stream>>>(Wrel1, Wroot1, scale0, shift0, yb, h);
  k_gather2<<<(NN * 16) / 256, 256, 0, stream>>>(yb, csr, cur, deg, h);
  k_stats_part<<<256, 256, 0, stream>>>(h, psum, pssq);
  k_bnfin<<<128, 64, 0, stream>>>(psum, pssq, gamma1, beta1, scale1, shift1, 256);
  k_final<<<(NN * 128) / 1024, 256, 0, stream>>>(h, scale1, shift1, (float*)d_out);
}

// Round 13
// 370.089 us; speedup vs baseline: 1.0766x; 1.0766x over previous
//
#include <hip/hip_runtime.h>

#define NN 50000
#define NE 800000
#define EPSV 1e-5f

typedef unsigned int u32;

// ws: aggx/yb [NN*64] | xb [NN*32] | st [1024] | deg [NN] | cur [NN] | csr [NE] | psum/pssq [2*400000]
#define WS_NEEDED ((size_t)(NN * 64 + NN * 32 + 1024 + NN + NN + NE + 2 * 400000) * 4)

__global__ void k_fallback(float* __restrict__ out) {
  int i = blockIdx.x * 256 + threadIdx.x;
  if (i < NN * 128) out[i] = 2.0f;
}

// mode: 1 = int64 (odd 32-bit words of first 32 values all zero), 0 = int32.
__global__ void k_detect(const int* __restrict__ ei, int* __restrict__ mode) {
  if (threadIdx.x == 0) {
    int all0 = 1;
    for (int i = 1; i < 64; i += 2) all0 &= (ei[i] == 0);
    *mode = all0;
  }
}

__device__ __forceinline__ void load_edge(const int* __restrict__ ei, int m, int e,
                                          int& src, int& dst) {
  if (m) { src = ei[e << 1]; dst = ei[(NE + e) << 1]; }
  else   { src = ei[e];      dst = ei[NE + e]; }
  src = min(max(src, 0), NN - 1);
  dst = min(max(dst, 0), NN - 1);
}

__global__ __launch_bounds__(256) void k_hist(
    const int* __restrict__ ei, const int* __restrict__ mode, int* __restrict__ deg) {
  int e = blockIdx.x * 256 + threadIdx.x;
  int src, dst;
  load_edge(ei, *mode, e, src, dst);
  atomicAdd(&deg[dst], 1);
}

// Stage 1: per-256-chunk sums of deg. 196 blocks.
__global__ __launch_bounds__(256) void k_scan1(
    const int* __restrict__ deg, int* __restrict__ bsum) {
  const int b = blockIdx.x, t = threadIdx.x;
  const int lane = t & 63, wave = t >> 6;
  int idx = b * 256 + t;
  int v = (idx < NN) ? deg[idx] : 0;
  for (int off = 32; off > 0; off >>= 1) v += __shfl_down(v, off);
  __shared__ int wt[4];
  if (lane == 0) wt[wave] = v;
  __syncthreads();
  if (t == 0) bsum[b] = wt[0] + wt[1] + wt[2] + wt[3];
}

// Stage 2: block offset = reduce(bsum[0..b)), then block-wide exclusive scan.
__global__ __launch_bounds__(256) void k_scan3(
    const int* __restrict__ deg, const int* __restrict__ bsum, int* __restrict__ cur) {
  const int b = blockIdx.x, t = threadIdx.x;
  const int lane = t & 63, wave = t >> 6;
  __shared__ int wt[4];
  __shared__ int boff;
  int pv = (t < b) ? bsum[t] : 0;  // b <= 195 < 256
  int r = pv;
  for (int off = 32; off > 0; off >>= 1) r += __shfl_down(r, off);
  if (lane == 0) wt[wave] = r;
  __syncthreads();
  if (t == 0) boff = wt[0] + wt[1] + wt[2] + wt[3];
  __syncthreads();
  int idx = b * 256 + t;
  int v = (idx < NN) ? deg[idx] : 0;
  int incl = v;
  for (int off = 1; off < 64; off <<= 1) {
    int u = __shfl_up(incl, off);
    if (lane >= off) incl += u;
  }
  if (lane == 63) wt[wave] = incl;
  __syncthreads();
  int woff = 0;
  for (int w = 0; w < wave; ++w) woff += wt[w];
  if (idx < NN) cur[idx] = boff + woff + incl - v;
}

__global__ __launch_bounds__(256) void k_place(
    const int* __restrict__ ei, const int* __restrict__ mode,
    int* __restrict__ cur, int* __restrict__ csr) {
  int e = blockIdx.x * 256 + threadIdx.x;
  int src, dst;
  load_edge(ei, *mode, e, src, dst);
  int pos = atomicAdd(&cur[dst], 1);
  csr[pos] = src;
}

__device__ __forceinline__ u32 pack_bf16(float lo, float hi) {
  union { float f; u32 u; } a, b;
  a.f = lo; b.f = hi;
  u32 ua = a.u + 0x7fffu + ((a.u >> 16) & 1u);
  u32 ub = b.u + 0x7fffu + ((b.u >> 16) & 1u);
  return (ua >> 16) | (ub & 0xffff0000u);
}
#define BFLO(u) __uint_as_float((u) << 16)
#define BFHI(u) __uint_as_float((u) & 0xffff0000u)

// xb[n*32+c] = pack(x[n*64+2c], x[n*64+2c+1])
__global__ __launch_bounds__(256) void k_pack(
    const float* __restrict__ x, u32* __restrict__ xb) {
  int i = blockIdx.x * 256 + threadIdx.x;  // over NN*32
  int n = i >> 5, c = i & 31;
  float2 v = *(const float2*)&x[n * 64 + c * 2];
  xb[i] = pack_bf16(v.x, v.y);
}

// aggx[n] = sum over incoming edges of unpack(xb[src]). 16 lanes/node, uint2/lane.
__global__ __launch_bounds__(256) void k_gather_xb(
    const u32* __restrict__ xb, const int* __restrict__ csr,
    const int* __restrict__ cur, const int* __restrict__ deg,
    float* __restrict__ aggx) {
  int tid = blockIdx.x * 256 + threadIdx.x;
  int n = tid >> 4, L = tid & 15;
  int end = cur[n];
  int i = end - deg[n];
  float a0 = 0.f, a1 = 0.f, a2 = 0.f, a3 = 0.f;
  float b0 = 0.f, b1 = 0.f, b2 = 0.f, b3 = 0.f;
  for (; i + 1 < end; i += 2) {
    int s0 = csr[i], s1 = csr[i + 1];
    uint2 u = *(const uint2*)&xb[s0 * 32 + 2 * L];
    uint2 w = *(const uint2*)&xb[s1 * 32 + 2 * L];
    a0 += BFLO(u.x); a1 += BFHI(u.x); a2 += BFLO(u.y); a3 += BFHI(u.y);
    b0 += BFLO(w.x); b1 += BFHI(w.x); b2 += BFLO(w.y); b3 += BFHI(w.y);
  }
  if (i < end) {
    int s0 = csr[i];
    uint2 u = *(const uint2*)&xb[s0 * 32 + 2 * L];
    a0 += BFLO(u.x); a1 += BFHI(u.x); a2 += BFLO(u.y); a3 += BFHI(u.y);
  }
  *(float4*)&aggx[n * 64 + 4 * L] =
      make_float4(a0 + b0, a1 + b1, a2 + b2, a3 + b3);
}

// h = [aggx | x] @ [Wrel0 ; Wroot0] (M=NN, K=128, N=128) + fused BN0 stat partials.
__global__ __launch_bounds__(256) void k_gemm_a(
    const float* __restrict__ x, const float* __restrict__ aggx,
    const float* __restrict__ Wrel, const float* __restrict__ Wroot,
    float* __restrict__ h, float* __restrict__ psum, float* __restrict__ pssq) {
  __shared__ float smem[16 * 132 + 16 * 128];
  float* As = smem;             // [kk][node], pad 132
  float* Bs = smem + 16 * 132;  // [kk][j]
  const int tid = threadIdx.x;
  const int nb = blockIdx.x * 128;
  const int tx = tid & 15;
  const int ty = tid >> 4;
  float acc[8][8];
#pragma unroll
  for (int i = 0; i < 8; ++i)
#pragma unroll
    for (int m = 0; m < 8; ++m) acc[i][m] = 0.f;

  for (int k0 = 0; k0 < 128; k0 += 16) {
    const float* Asrc = (k0 < 64) ? aggx : x;
    const float* Bsrc = (k0 < 64) ? Wrel : Wroot;
    const int kbase = (k0 < 64) ? k0 : (k0 - 64);
    __syncthreads();
#pragma unroll
    for (int it = 0; it < 2; ++it) {  // A: 128 nodes x 16 k = 512 float4
      int fid = tid + 256 * it;
      int node = fid & 127, kq = (fid >> 7) << 2;  // lane-stride-1 LDS writes
      int n = nb + node;
      float4 v = (n < NN) ? *(const float4*)&Asrc[n * 64 + kbase + kq]
                          : make_float4(0.f, 0.f, 0.f, 0.f);
      As[(kq + 0) * 132 + node] = v.x;
      As[(kq + 1) * 132 + node] = v.y;
      As[(kq + 2) * 132 + node] = v.z;
      As[(kq + 3) * 132 + node] = v.w;
    }
#pragma unroll
    for (int it = 0; it < 2; ++it) {  // B: 16 x 128 = 512 float4
      int fid = tid + 256 * it;
      int kk = fid >> 5, j4 = (fid & 31) << 2;
      *(float4*)&Bs[kk * 128 + j4] = *(const float4*)&Bsrc[(kbase + kk) * 128 + j4];
    }
    __syncthreads();
#pragma unroll 4
    for (int kk = 0; kk < 16; ++kk) {
      float a[8], b[8];
      *(float4*)&a[0] = *(const float4*)&As[kk * 132 + ty * 8];
      *(float4*)&a[4] = *(const float4*)&As[kk * 132 + ty * 8 + 4];
#pragma unroll
      for (int m = 0; m < 8; ++m) b[m] = Bs[kk * 128 + tx + 16 * m];
#pragma unroll
      for (int i = 0; i < 8; ++i)
#pragma unroll
        for (int m = 0; m < 8; ++m) acc[i][m] += a[i] * b[m];
    }
  }
#pragma unroll
  for (int i = 0; i < 8; ++i) {
    int n = nb + ty * 8 + i;
    if (n < NN) {
#pragma unroll
      for (int m = 0; m < 8; ++m) h[n * 128 + tx + 16 * m] = acc[i][m];
    }
  }
  float ps[8], qs[8];
#pragma unroll
  for (int m = 0; m < 8; ++m) {
    float s = 0.f, q = 0.f;
#pragma unroll
    for (int i = 0; i < 8; ++i) { s += acc[i][m]; q += acc[i][m] * acc[i][m]; }
    ps[m] = s; qs[m] = q;
  }
  __syncthreads();  // safe LDS reuse
  float* S = smem;          // [16][128]
  float* Q = smem + 2048;   // [16][128]
#pragma unroll
  for (int m = 0; m < 8; ++m) {
    S[ty * 128 + tx + 16 * m] = ps[m];
    Q[ty * 128 + tx + 16 * m] = qs[m];
  }
  __syncthreads();
  if (tid < 128) {
    float s = 0.f, q = 0.f;
#pragma unroll
    for (int g = 0; g < 16; ++g) { s += S[g * 128 + tid]; q += Q[g * 128 + tid]; }
    psum[blockIdx.x * 128 + tid] = s;
    pssq[blockIdx.x * 128 + tid] = q;
  }
}

// Parallel partial reduction -> scale/shift. 128 blocks (one per channel) x 64 lanes.
__global__ __launch_bounds__(64) void k_bnfin(
    const float* __restrict__ psum, const float* __restrict__ pssq,
    const float* __restrict__ gamma, const float* __restrict__ beta,
    float* __restrict__ scale, float* __restrict__ shift, int P) {
  const int c = blockIdx.x;
  const int t = threadIdx.x;
  float S = 0.f, Q = 0.f;
  for (int p = t; p < P; p += 64) {
    S += psum[p * 128 + c];
    Q += pssq[p * 128 + c];
  }
  for (int off = 32; off > 0; off >>= 1) {
    S += __shfl_down(S, off);
    Q += __shfl_down(Q, off);
  }
  if (t == 0) {
    float mean = S * (1.0f / NN);
    float var = fmaxf(Q * (1.0f / NN) - mean * mean, 0.f);
    float sc = gamma[c] * rsqrtf(var + EPSV);
    scale[c] = sc;
    shift[c] = beta[c] - mean * sc;
  }
}

// t = relu(bn(h)); yb = bf16(t @ Wrel1) packed; h <- t @ Wroot1 (in place).
// K processed in two 64-wide phases so As is 17.4 KB (LDS 50.8 -> 33.8 KB,
// 3 -> 4 blocks/CU). Compute mapping / yb packing identical to the passing
// round-12 kernel; only staging is phased.
__global__ __launch_bounds__(256) void k_gemm_b(
    const float* __restrict__ Wrel, const float* __restrict__ Wroot,
    const float* __restrict__ scale, const float* __restrict__ shift,
    u32* __restrict__ yb, float* __restrict__ h) {
  __shared__ float As[64 * 68];   // [kk 0..63][node], pad 68
  __shared__ float Bs[16 * 256];
  const int tid = threadIdx.x;
  const int nb = blockIdx.x * 64;
  const int tx = tid & 31;
  const int ty = tid >> 5;
  float acc[8][8];
#pragma unroll
  for (int i = 0; i < 8; ++i)
#pragma unroll
    for (int m = 0; m < 8; ++m) acc[i][m] = 0.f;

  for (int ph = 0; ph < 2; ++ph) {
    __syncthreads();  // previous phase's compute done before As overwrite
#pragma unroll
    for (int it = 0; it < 4; ++it) {  // stage As = relu(bn(h)) for k in [64ph, 64ph+64)
      int fid = tid + 256 * it;       // 0..1023
      int node = fid & 63, kq = (fid >> 6) << 2;  // lane-stride-1 LDS writes
      int n = nb + node;
      int kg = ph * 64 + kq;
      float4 v = (n < NN) ? *(const float4*)&h[n * 128 + kg]
                          : make_float4(0.f, 0.f, 0.f, 0.f);
      float4 sc = *(const float4*)&scale[kg];
      float4 sh = *(const float4*)&shift[kg];
      As[(kq + 0) * 68 + node] = fmaxf(v.x * sc.x + sh.x, 0.f);
      As[(kq + 1) * 68 + node] = fmaxf(v.y * sc.y + sh.y, 0.f);
      As[(kq + 2) * 68 + node] = fmaxf(v.z * sc.z + sh.z, 0.f);
      As[(kq + 3) * 68 + node] = fmaxf(v.w * sc.w + sh.w, 0.f);
    }
    for (int k0 = 0; k0 < 64; k0 += 16) {
      __syncthreads();  // As staged / previous tile's compute done
#pragma unroll
      for (int it = 0; it < 4; ++it) {  // B: 16 x 256
        int fid = tid + 256 * it;
        int kk = fid >> 6, j4 = (fid & 63) << 2;
        int kg = ph * 64 + k0 + kk;
        const float* Bsrc = (j4 < 128) ? &Wrel[kg * 128 + j4]
                                       : &Wroot[kg * 128 + (j4 - 128)];
        *(float4*)&Bs[kk * 256 + j4] = *(const float4*)Bsrc;
      }
      __syncthreads();
#pragma unroll 4
      for (int kk = 0; kk < 16; ++kk) {
        float a[8], b[8];
        *(float4*)&a[0] = *(const float4*)&As[(k0 + kk) * 68 + ty * 8];
        *(float4*)&a[4] = *(const float4*)&As[(k0 + kk) * 68 + ty * 8 + 4];
#pragma unroll
        for (int m = 0; m < 8; ++m) b[m] = Bs[kk * 256 + tx + 32 * m];
#pragma unroll
        for (int i = 0; i < 8; ++i)
#pragma unroll
          for (int m = 0; m < 8; ++m) acc[i][m] += a[i] * b[m];
      }
    }
  }
#pragma unroll
  for (int i = 0; i < 8; ++i) {
    int n = nb + ty * 8 + i;
    if (n < NN) {
      yb[n * 64 + tx]      = pack_bf16(acc[i][0], acc[i][1]);
      yb[n * 64 + tx + 32] = pack_bf16(acc[i][2], acc[i][3]);
      float* hp = h + n * 128;
      hp[tx]      = acc[i][4];
      hp[tx + 32] = acc[i][5];
      hp[tx + 64] = acc[i][6];
      hp[tx + 96] = acc[i][7];
    }
  }
}

// h[n] += sum over incoming edges of unpack(yb[src]) + fused BN1 stat partials.
// 16 lanes/node, uint4/lane, 2x ILP unroll.
__global__ __launch_bounds__(256) void k_gather2(
    const u32* __restrict__ yb, const int* __restrict__ csr,
    const int* __restrict__ cur, const int* __restrict__ deg,
    float* __restrict__ h, float* __restrict__ psum, float* __restrict__ pssq) {
  int tid = blockIdx.x * 256 + threadIdx.x;
  int n = tid >> 4;
  int L = threadIdx.x & 15;
  int base = L << 2;
  int c0 = (base & 31) + ((base >> 5) << 6);
  int end = cur[n];
  int i = end - deg[n];
  float lo0 = 0.f, lo1 = 0.f, lo2 = 0.f, lo3 = 0.f;
  float hi0 = 0.f, hi1 = 0.f, hi2 = 0.f, hi3 = 0.f;
  float mo0 = 0.f, mo1 = 0.f, mo2 = 0.f, mo3 = 0.f;
  float ni0 = 0.f, ni1 = 0.f, ni2 = 0.f, ni3 = 0.f;
  for (; i + 1 < end; i += 2) {
    int s0 = csr[i], s1 = csr[i + 1];
    uint4 v = *(const uint4*)&yb[s0 * 64 + base];
    uint4 w = *(const uint4*)&yb[s1 * 64 + base];
    lo0 += BFLO(v.x); hi0 += BFHI(v.x);
    lo1 += BFLO(v.y); hi1 += BFHI(v.y);
    lo2 += BFLO(v.z); hi2 += BFHI(v.z);
    lo3 += BFLO(v.w); hi3 += BFHI(v.w);
    mo0 += BFLO(w.x); ni0 += BFHI(w.x);
    mo1 += BFLO(w.y); ni1 += BFHI(w.y);
    mo2 += BFLO(w.z); ni2 += BFHI(w.z);
    mo3 += BFLO(w.w); ni3 += BFHI(w.w);
  }
  if (i < end) {
    int s = csr[i];
    uint4 v = *(const uint4*)&yb[s * 64 + base];
    lo0 += BFLO(v.x); hi0 += BFHI(v.x);
    lo1 += BFLO(v.y); hi1 += BFHI(v.y);
    lo2 += BFLO(v.z); hi2 += BFHI(v.z);
    lo3 += BFLO(v.w); hi3 += BFHI(v.w);
  }
  float4 A = *(const float4*)&h[n * 128 + c0];
  float4 B = *(const float4*)&h[n * 128 + c0 + 32];
  float4 R0 = make_float4(A.x + lo0 + mo0, A.y + lo1 + mo1,
                          A.z + lo2 + mo2, A.w + lo3 + mo3);
  float4 R1 = make_float4(B.x + hi0 + ni0, B.y + hi1 + ni1,
                          B.z + hi2 + ni2, B.w + hi3 + ni3);
  *(float4*)&h[n * 128 + c0]      = R0;
  *(float4*)&h[n * 128 + c0 + 32] = R1;
  // Fused BN1 stat partials: block covers 16 nodes x 128 channels.
  __shared__ float S[16 * 132], Q[16 * 132];
  const int nl = threadIdx.x >> 4;
  *(float4*)&S[nl * 132 + c0] = R0;
  *(float4*)&S[nl * 132 + c0 + 32] = R1;
  *(float4*)&Q[nl * 132 + c0] =
      make_float4(R0.x * R0.x, R0.y * R0.y, R0.z * R0.z, R0.w * R0.w);
  *(float4*)&Q[nl * 132 + c0 + 32] =
      make_float4(R1.x * R1.x, R1.y * R1.y, R1.z * R1.z, R1.w * R1.w);
  __syncthreads();
  const int t = threadIdx.x;
  if (t < 128) {
    float s = 0.f, q = 0.f;
#pragma unroll
    for (int g = 0; g < 16; ++g) { s += S[g * 132 + t]; q += Q[g * 132 + t]; }
    psum[blockIdx.x * 128 + t] = s;
    pssq[blockIdx.x * 128 + t] = q;
  }
}

__global__ __launch_bounds__(256) void k_final(
    const float* __restrict__ h, const float* __restrict__ scale,
    const float* __restrict__ shift, float* __restrict__ out) {
  int tid = blockIdx.x * 256 + threadIdx.x;
  int base = tid << 2;
  int f4 = base & 127;
  float4 v = *(const float4*)&h[base];
  float4 sc = *(const float4*)&scale[f4];
  float4 sh = *(const float4*)&shift[f4];
  *(float4*)&out[base] = make_float4(v.x * sc.x + sh.x, v.y * sc.y + sh.y,
                                     v.z * sc.z + sh.z, v.w * sc.w + sh.w);
}

extern "C" void kernel_launch(void* const* d_in, const int* in_sizes, int n_in,
                              void* d_out, int out_size, void* d_ws, size_t ws_size,
                              hipStream_t stream) {
  if (ws_size < WS_NEEDED) {
    k_fallback<<<(NN * 128 + 255) / 256, 256, 0, stream>>>((float*)d_out);
    return;
  }
  const float* x      = (const float*)d_in[0];
  const int*   ei     = (const int*)d_in[1];
  const float* Wrel0  = (const float*)d_in[2];
  // d_in[3] = b_rel0: per-channel constant pre-BN -> cancels in BN, unused
  const float* Wroot0 = (const float*)d_in[4];
  const float* gamma0 = (const float*)d_in[5];
  const float* beta0  = (const float*)d_in[6];
  const float* Wrel1  = (const float*)d_in[7];
  // d_in[8] = b_rel1: unused (cancels in BN)
  const float* Wroot1 = (const float*)d_in[9];
  const float* gamma1 = (const float*)d_in[10];
  const float* beta1  = (const float*)d_in[11];

  float* aggx = (float*)d_ws;            // NN*64 (reused as yb after gemm_a)
  u32*   yb   = (u32*)d_ws;
  u32*   xb   = (u32*)(aggx + NN * 64);  // NN*32
  float* st   = (float*)(xb + NN * 32);  // 1024 floats
  float* scale0 = st;       float* shift0 = st + 128;
  float* scale1 = st + 256; float* shift1 = st + 384;
  int* mode = (int*)(st + 512);
  int* bsum = (int*)(st + 576);          // 196 ints
  int* deg = (int*)(st + 1024);          // NN
  int* cur = deg + NN;                   // NN
  int* csr = cur + NN;                   // NE
  float* psum = (float*)(csr + NE);      // 400000 (3125*128)
  float* pssq = psum + 400000;           // 400000
  float* h = (float*)d_out;              // h lives in d_out; k_final is in-place

  hipMemsetAsync(deg, 0, (size_t)NN * 4, stream);
  k_detect<<<1, 64, 0, stream>>>(ei, mode);
  k_hist<<<NE / 256, 256, 0, stream>>>(ei, mode, deg);
  k_scan1<<<196, 256, 0, stream>>>(deg, bsum);
  k_scan3<<<196, 256, 0, stream>>>(deg, bsum, cur);
  k_place<<<NE / 256, 256, 0, stream>>>(ei, mode, cur, csr);

  k_pack<<<(NN * 32) / 256, 256, 0, stream>>>(x, xb);
  k_gather_xb<<<(NN * 16) / 256, 256, 0, stream>>>(xb, csr, cur, deg, aggx);
  k_gemm_a<<<(NN + 127) / 128, 256, 0, stream>>>(x, aggx, Wrel0, Wroot0, h, psum, pssq);
  k_bnfin<<<128, 64, 0, stream>>>(psum, pssq, gamma0, beta0, scale0, shift0, 391);
  k_gemm_b<<<(NN + 63) / 64, 256, 0, stream>>>(Wrel1, Wroot1, scale0, shift0, yb, h);
  k_gather2<<<(NN * 16) / 256, 256, 0, stream>>>(yb, csr, cur, deg, h, psum, pssq);
  k_bnfin<<<128, 64, 0, stream>>>(psum, pssq, gamma1, beta1, scale1, shift1, 3125);
  k_final<<<(NN * 128) / 1024, 256, 0, stream>>>(h, scale1, shift1, (float*)d_out);
}